// Round 12
// baseline (1590.381 us; speedup 1.0000x reference)
//
#include <hip/hip_runtime.h>
#include <hip/hip_bf16.h>

// RNN: B=4096, T=1024, H=40, K=41. fp32 compute & state (dtype autodetected).
// Round-22: TWO elements per wave -- share each streamed weight across els.
// R21 post-mortem: asm-pin failed AGAIN (VGPR 60); 8 residency attempts dead.
// The cross-round invariant: every structure streams ~320 KB of weights per
// CU-step (each lane re-streams all its rows' weights each step, serving ONE
// element). 320KB / 2000cyc ~= 160 B/cyc/CU = L1 return ceiling -> THE wall.
// Lever never pulled: amortize each weight over multiple elements.
//   Grid 2048 x 64 thr (single-wave blocks, proven R18/R19); block owns els
//   {2b, 2b+1}: sH[2][44], sA[2][84]. Inner loops load each weight f4 ONCE
//   and use it for el0 AND el1 back-to-back (adjacent uses -> remat
//   materializes once). Weight bytes per el-step HALVE. Two independent
//   recurrence chains per wave also double ILP vs the LDS/FMA latency chain
//   -- wins under either bandwidth- or chain-theory.
// Occupancy drops to 2 waves/SIMD (by design; waves carry 2x work).
// Slots/maps/math per el identical to R18-R21 (absmax-stable):
//   kh=lane&1, w=lane>>1; slot0/1: L1 rows {2w,2w+1}; slot2: w>=16 ? L1 row
//   48+w : L2 row w; slot3: w<24 ? L2 row 16+w : w==24 ? OUTPUT : idle.
// Phase A: slots 0,1,2 vs state (both els); Phase B: slots 2,3 vs acts.
// WFENCE (R19, zero-cost) between phases. pack_weights (R20) unchanged.

#define B_SZ 4096
#define T_SZ 1024
#define HID  40
#define WSTRIDE 88   // floats per lane slice in ws (352 B, 16B-aligned)

typedef unsigned short u16;
typedef unsigned int   u32;
typedef float f2 __attribute__((ext_vector_type(2)));
typedef float f4 __attribute__((ext_vector_type(4)));

// Zero-cost single-wave "barrier" (proven R19): LDS ops of one wave are
// processed in program order; only forbid COMPILER reordering.
#define WFENCE() do {                      \
    asm volatile("" ::: "memory");         \
    __builtin_amdgcn_wave_barrier();       \
    asm volatile("" ::: "memory");         \
  } while (0)

__device__ __forceinline__ float bf2f(u16 v) {
  union { u32 u; float f; } c; c.u = ((u32)v) << 16; return c.f;
}

// Proven rounds 3-21: true-bf16 weights all have |w| <= 1/sqrt(41) ~ 0.156;
// fp32 data read as bf16 halfwords exceeds 0.2 with P ~ 1-1e-10.
__device__ __forceinline__ bool detect_bf16(const void* w) {
  const u16* p = (const u16*)w;
  bool bf = true;
  for (int i = 0; i < 64; ++i) {
    float f = bf2f(p[i]);
    if (!(fabsf(f) <= 0.2f)) bf = false;
  }
  return bf;
}

__device__ __forceinline__ float ldgr(bool bf, const void* p, long i) {
  return bf ? bf2f(((const u16*)p)[i]) : ((const float*)p)[i];
}

// Partner value from lane^1 (quad_perm [1,0,3,2]). VALU pipe, no LDS.
__device__ __forceinline__ float pair_other(float x) {
  return __int_as_float(__builtin_amdgcn_update_dpp(
      0, __float_as_int(x), 0xB1, 0xF, 0xF, true));
}

// ---- Pack kernel: per-lane fp32 weight slices into ws (R20, unchanged) ----
__global__ __launch_bounds__(64)
void pack_weights(const void* __restrict__ h2h_w1, const void* __restrict__ h2h_b1,
                  const void* __restrict__ h2h_w2, const void* __restrict__ h2h_b2,
                  const void* __restrict__ h2o_w1, const void* __restrict__ h2o_b1,
                  const void* __restrict__ h2o_w2, const void* __restrict__ h2o_b2,
                  float* __restrict__ ws) {
  const bool bf  = detect_bf16(h2h_w1);
  const int lane = threadIdx.x;       // 0..63
  const int kh   = lane & 1;
  const int w    = lane >> 1;
  const int koff = kh * 20;

  const bool hh01 = (2 * w < HID);
  const void* p01 = hh01 ? h2h_w1 : h2o_w1;
  const long  jr0 = hh01 ? 2 * w : 2 * w - HID;
  const bool  s2A = (w >= 16);
  const void* p2  = s2A ? h2o_w1 : h2h_w2;
  const long  o2  = s2A ? ((long)(8 + w) * 41 + 1 + koff) : ((long)w * HID + koff);
  const bool  isOut = (w == 24);
  const void* p3  = isOut ? h2o_w2 : h2h_w2;
  const long  o3  = isOut ? (long)koff : ((long)(16 + (w < 24 ? w : 0)) * HID + koff);

  float* dst = ws + (long)lane * WSTRIDE;
  for (int i = 0; i < 20; ++i) {
    dst[i]      = ldgr(bf, p01, jr0 * 41 + 1 + koff + i);
    dst[20 + i] = ldgr(bf, p01, (jr0 + 1) * 41 + 1 + koff + i);
    dst[40 + i] = ldgr(bf, p2, o2 + i);
    dst[60 + i] = ldgr(bf, p3, o3 + i);
  }
  float wu0 = 0, wu1 = 0, wu2 = 0, ba0 = 0, ba1 = 0, ba2 = 0, bb2 = 0, bb3 = 0;
  if (kh == 0) {
    const void* b1p = hh01 ? h2h_b1 : h2o_b1;
    wu0 = ldgr(bf, p01, jr0 * 41);
    wu1 = ldgr(bf, p01, (jr0 + 1) * 41);
    ba0 = ldgr(bf, b1p, jr0);
    ba1 = ldgr(bf, b1p, jr0 + 1);
    if (s2A) { wu2 = ldgr(bf, h2o_w1, (long)(8 + w) * 41); ba2 = ldgr(bf, h2o_b1, 8 + w); }
    else     { bb2 = ldgr(bf, h2h_b2, w); }
    if (isOut)       bb3 = ldgr(bf, h2o_b2, 0);
    else if (w < 24) bb3 = ldgr(bf, h2h_b2, 16 + w);
  }
  dst[80] = wu0; dst[81] = wu1; dst[82] = wu2; dst[83] = ba0;
  dst[84] = ba1; dst[85] = ba2; dst[86] = bb2; dst[87] = bb3;
}

template <bool BF>
__global__ __launch_bounds__(64)
void rnn_kernel(const void* __restrict__ inp, const void* __restrict__ h2h_w1,
                const float* __restrict__ ws, void* __restrict__ out) {
  __shared__ __align__(16) float sH[2][44];  // state,  per el
  __shared__ __align__(16) float sA[2][84];  // L1 acts, per el

  if (detect_bf16(h2h_w1) != BF) return;  // wrong-dtype instantiation exits

  const int lane = threadIdx.x & 63;
  const int kh   = lane & 1;          // K-half: 0 -> u + k0..19, 1 -> k20..39
  const int w    = lane >> 1;         // worker 0..31
  const int koff = kh * 20;
  const bool s2A   = (w >= 16);
  const bool isOut = (w == 24);

  // Weight stream base (per-lane packed fp32; loads stay in-loop, shared
  // at the use site by both els -> one materialization per step).
  const f4* wq = (const f4*)(ws + (long)lane * WSTRIDE);
  const float* wsc = ws + (long)lane * WSTRIDE + 80;
  const float wu0 = wsc[0], wu1 = wsc[1], wu2 = wsc[2], ba0 = wsc[3];
  const float ba1 = wsc[4], ba2 = wsc[5], bb2 = wsc[6], bb3 = wsc[7];

  for (int i = lane; i < 2 * 44; i += 64) ((float*)sH)[i] = 0.f;
  WFENCE();   // single wave: zeroing writes ordered before first reads

  const long base0 = (long)(blockIdx.x * 2) * T_SZ;       // el 0
  const long base1 = base0 + T_SZ;                        // el 1
  float u0 = BF ? bf2f(((const u16*)inp)[base0]) : ((const float*)inp)[base0];
  float u1 = BF ? bf2f(((const u16*)inp)[base1]) : ((const float*)inp)[base1];

  const f4* hp0 = (const f4*)(&sH[0][koff]);
  const f4* hp1 = (const f4*)(&sH[1][koff]);
  const f4* ap0 = (const f4*)(&sA[0][isOut ? 40 + koff : koff]);
  const f4* ap1 = (const f4*)(&sA[1][isOut ? 40 + koff : koff]);
  const bool wrA2 = s2A && (kh == 0);
  const bool wr2  = (!s2A) && (kh == 0);        // w<16: new h[w]
  const bool wr3  = (w < 24) && (kh == 0);      // new h[16+w]
  const bool wrY  = isOut && (kh == 0);

  for (int t = 0; t < T_SZ; ++t) {
    const float u0n = (t + 1 < T_SZ)
        ? (BF ? bf2f(((const u16*)inp)[base0 + t + 1]) : ((const float*)inp)[base0 + t + 1]) : 0.f;
    const float u1n = (t + 1 < T_SZ)
        ? (BF ? bf2f(((const u16*)inp)[base1 + t + 1]) : ((const float*)inp)[base1 + t + 1]) : 0.f;

    // ---------- Phase A: L1 rows (slots 0,1,2) vs state, BOTH els ----------
    {
      f2 a00 = {0,0}, a10 = {0,0}, a20 = {0,0};   // el0 accums (slot0,1,2)
      f2 a01 = {0,0}, a11 = {0,0}, a21 = {0,0};   // el1 accums
#pragma unroll
      for (int m = 0; m < 5; ++m) {
        const f4 w0 = wq[m], w1 = wq[5 + m], w2 = wq[10 + m];  // ONE load each
        const f4 h0 = hp0[m], h1 = hp1[m];
        const f2 h0A = {h0.x, h0.y}, h0B = {h0.z, h0.w};
        const f2 h1A = {h1.x, h1.y}, h1B = {h1.z, h1.w};
        const f2 w0A = {w0.x, w0.y}, w0B = {w0.z, w0.w};
        const f2 w1A = {w1.x, w1.y}, w1B = {w1.z, w1.w};
        const f2 w2A = {w2.x, w2.y}, w2B = {w2.z, w2.w};
        a00 = h0A * w0A + a00;  a01 = h1A * w0A + a01;   // weight reused
        a00 = h0B * w0B + a00;  a01 = h1B * w0B + a01;
        a10 = h0A * w1A + a10;  a11 = h1A * w1A + a11;
        a10 = h0B * w1B + a10;  a11 = h1B * w1B + a11;
        a20 = h0A * w2A + a20;  a21 = h1A * w2A + a21;
        a20 = h0B * w2B + a20;  a21 = h1B * w2B + a21;
      }
      // el0 tail
      {
        const float v0 = fmaf(u0, wu0, ba0) + a00.x + a00.y;
        const float v1 = fmaf(u0, wu1, ba1) + a10.x + a10.y;
        const float v2 = fmaf(u0, wu2, ba2) + a20.x + a20.y;
        const float t0 = v0 + pair_other(v0);
        const float t1 = v1 + pair_other(v1);
        const float t2 = v2 + pair_other(v2);
        if (kh == 0) {
          f2 act; act.x = fmaxf(t0, 0.01f * t0); act.y = fmaxf(t1, 0.01f * t1);
          *(f2*)(&sA[0][2 * w]) = act;
        }
        if (wrA2) sA[0][48 + w] = fmaxf(t2, 0.01f * t2);
      }
      // el1 tail
      {
        const float v0 = fmaf(u1, wu0, ba0) + a01.x + a01.y;
        const float v1 = fmaf(u1, wu1, ba1) + a11.x + a11.y;
        const float v2 = fmaf(u1, wu2, ba2) + a21.x + a21.y;
        const float t0 = v0 + pair_other(v0);
        const float t1 = v1 + pair_other(v1);
        const float t2 = v2 + pair_other(v2);
        if (kh == 0) {
          f2 act; act.x = fmaxf(t0, 0.01f * t0); act.y = fmaxf(t1, 0.01f * t1);
          *(f2*)(&sA[1][2 * w]) = act;
        }
        if (wrA2) sA[1][48 + w] = fmaxf(t2, 0.01f * t2);
      }
    }
    WFENCE();   // in-wave DS order: acts written before phase-B reads

    // ---------- Phase B: L2 rows + output (slots 2,3), BOTH els ----------
    {
      f2 b20 = {0,0}, b30 = {0,0};   // el0
      f2 b21 = {0,0}, b31 = {0,0};   // el1
#pragma unroll
      for (int m = 0; m < 5; ++m) {
        const f4 w2 = wq[10 + m], w3 = wq[15 + m];   // ONE load each
        const f4 a0 = ap0[m], a1 = ap1[m];
        const f2 a0A = {a0.x, a0.y}, a0B = {a0.z, a0.w};
        const f2 a1A = {a1.x, a1.y}, a1B = {a1.z, a1.w};
        const f2 w2A = {w2.x, w2.y}, w2B = {w2.z, w2.w};
        const f2 w3A = {w3.x, w3.y}, w3B = {w3.z, w3.w};
        b20 = a0A * w2A + b20;  b21 = a1A * w2A + b21;
        b20 = a0B * w2B + b20;  b21 = a1B * w2B + b21;
        b30 = a0A * w3A + b30;  b31 = a1A * w3A + b31;
        b30 = a0B * w3B + b30;  b31 = a1B * w3B + b31;
      }
      // el0 tail
      {
        const float v2 = bb2 + b20.x + b20.y;
        const float v3 = bb3 + b30.x + b30.y;
        const float t2 = v2 + pair_other(v2);
        const float t3 = v3 + pair_other(v3);
        if (wr2) sH[0][w] = t2;
        if (wr3) sH[0][16 + w] = t3;
        if (wrY) {
          if (BF) ((__hip_bfloat16*)out)[base0 + t] = __float2bfloat16(t3);
          else    ((float*)out)[base0 + t] = t3;
        }
      }
      // el1 tail
      {
        const float v2 = bb2 + b21.x + b21.y;
        const float v3 = bb3 + b31.x + b31.y;
        const float t2 = v2 + pair_other(v2);
        const float t3 = v3 + pair_other(v3);
        if (wr2) sH[1][w] = t2;
        if (wr3) sH[1][16 + w] = t3;
        if (wrY) {
          if (BF) ((__hip_bfloat16*)out)[base1 + t] = __float2bfloat16(t3);
          else    ((float*)out)[base1 + t] = t3;
        }
      }
    }
    WFENCE();   // acts consumed before next step's phase-A overwrites

    u0 = u0n; u1 = u1n;
  }
}

extern "C" void kernel_launch(void* const* d_in, const int* in_sizes, int n_in,
                              void* d_out, int out_size, void* d_ws, size_t ws_size,
                              hipStream_t stream) {
  (void)in_sizes; (void)n_in; (void)out_size;
  if (ws_size < (size_t)(64 * WSTRIDE * sizeof(float))) return;  // need 22.5 KB
  float* ws = (float*)d_ws;
  pack_weights<<<dim3(1), dim3(64), 0, stream>>>(
      d_in[1], d_in[2], d_in[3], d_in[4],
      d_in[5], d_in[6], d_in[7], d_in[8], ws);
  rnn_kernel<false><<<dim3(B_SZ / 2), dim3(64), 0, stream>>>(
      d_in[0], d_in[1], ws, d_out);
  rnn_kernel<true><<<dim3(B_SZ / 2), dim3(64), 0, stream>>>(
      d_in[0], d_in[1], ws, d_out);
}

// Round 13
// 752.248 us; speedup vs baseline: 2.1142x; 2.1142x over previous
//
#include <hip/hip_runtime.h>
#include <hip/hip_bf16.h>

// RNN: B=4096, T=1024, H=40, K=41. fp32 compute & state (dtype autodetected).
// Round-23: R15 champion structure (743us) + bf16-PACKED weight stream.
// R22 post-mortem: sharing weights across 2 els DOUBLED per-el cost (932 vs
// 478 cyc/el-step) -- latency exposure, not bytes, is the wall. Model: the
// allocator holds ~112 VGPR and remats ~half the weights every step in
// load->use clusters; R15's remat path is 2x global_load_ushort + 2 shifts
// PER f2 (dataset is bf16). Fix the STREAM FORM, keep the champion structure:
//   pack_weights (1 block, once/launch): per-thread slice of 88 u32 in d_ws:
//   [80 bf16-PAIRS packed as u32 (4 slots x 20)] + [8 fp32 scalars].
//   Main loop expands on use: lo=u<<16, hi=u&0xffff0000 (exact bf16->fp32),
//   feeding the SAME pk_fma in the SAME order -> bit-identical to R15.
//   Remat stream: ~100 ushort loads -> ~13 dwordx4 loads per wave-step
//   (8x fewer latency events); bytes halve; 1 u32 = 2 weights doubles
//   resident coverage. Cost: +2 expand VALU/pair at use -- net win.
// Structure (R15 verbatim): 1024 blocks x 128 thr (2 waves), 4 els/block,
//   el=lane&3, w=wv*16+(lane>>2). Wave0: A-rows {3w,3w+1,3w+2}, B: w<8 ->
//   row 32+w, w==8 -> OUTPUT. Wave1: A-rows {48+2(w-16),+1}, B-rows
//   {2(w-16),+1}. 2 barriers/step. Fallback (small ws / fp32): R15 verbatim.

#define B_SZ 4096
#define T_SZ 1024
#define HID  40
#define WSLICE 88   // u32 words per thread slice (352 B, 16B-aligned)

typedef unsigned short u16;
typedef unsigned int   u32;
typedef float f2 __attribute__((ext_vector_type(2)));

__device__ __forceinline__ float bf2f(u16 v) {
  union { u32 u; float f; } c; c.u = ((u32)v) << 16; return c.f;
}

template <bool BF>
__device__ __forceinline__ float ldg(const void* p, long i) {
  if (BF) return bf2f(((const u16*)p)[i]);
  return ((const float*)p)[i];
}

template <bool BF>
__device__ __forceinline__ f2 ldg2(const void* p, long i) {
  f2 r;
  r.x = ldg<BF>(p, i + 0);
  r.y = ldg<BF>(p, i + 1);
  return r;
}

// Proven rounds 3-22: true-bf16 weights all have |w| <= 1/sqrt(41) ~ 0.156;
// fp32 data read as bf16 halfwords exceeds 0.2 with P ~ 1-1e-10.
__device__ __forceinline__ bool detect_bf16(const void* w) {
  const u16* p = (const u16*)w;
  bool bf = true;
  for (int i = 0; i < 64; ++i) {
    float f = bf2f(p[i]);
    if (!(fabsf(f) <= 0.2f)) bf = false;
  }
  return bf;
}

// Expand a packed bf16 pair -> f2 (EXACT, 2 VALU ops).
__device__ __forceinline__ f2 bexp(u32 u) {
  f2 r;
  r.x = __uint_as_float(u << 16);
  r.y = __uint_as_float(u & 0xffff0000u);
  return r;
}

// ---- Pack kernel: per-thread bf16-pair slices into ws (bf16 datasets) ----
__global__ __launch_bounds__(128)
void pack_weights(const void* __restrict__ h2h_w1, const void* __restrict__ h2h_b1,
                  const void* __restrict__ h2h_w2, const void* __restrict__ h2h_b2,
                  const void* __restrict__ h2o_w1, const void* __restrict__ h2o_b1,
                  const void* __restrict__ h2o_w2, const void* __restrict__ h2o_b2,
                  u32* __restrict__ ws) {
  const int tid  = threadIdx.x;            // 0..127, mirrors main kernel
  const int lane = tid & 63;
  const int wv   = tid >> 6;
  const int w    = wv * 16 + (lane >> 2);
  const int a0 = (wv == 0) ? 3 * w : 48 + 2 * (w - 16);
  const int nA = (wv == 0) ? 3 : 2;
  const int rB = (wv == 0) ? ((w < 8) ? 32 + w : ((w == 8) ? 40 : -1)) : 2 * (w - 16);

  const u16* w1h = (const u16*)h2h_w1;   // read as bf16 halfwords; if the
  const u16* w1o = (const u16*)h2o_w1;   // dataset is fp32 this data is
  const u16* w2h = (const u16*)h2h_w2;   // garbage but NEVER consumed
  const u16* w2o = (const u16*)h2o_w2;   // (fallback kernel runs instead).

  u32* dst = ws + (long)tid * WSLICE;
  float* ds = (float*)(dst + 80);
  for (int k = 0; k < 80; ++k) dst[k] = 0u;
  for (int k = 0; k < 8; ++k)  ds[k] = 0.f;

  for (int q = 0; q < 3; ++q) {
    if (q < nA) {                       // A-slots: L1 row a0+q
      const int  j  = a0 + q;
      const bool hh = (j < HID);
      const u16* wb = hh ? w1h : w1o;
      const long jr = hh ? j : j - HID;
      for (int i = 0; i < 20; ++i) {
        const u32 lo = wb[jr * 41 + 1 + 2 * i];
        const u32 hi = wb[jr * 41 + 2 + 2 * i];
        dst[20 * q + i] = lo | (hi << 16);
      }
      ds[q]     = bf2f(wb[jr * 41]);                               // wu[q]
      ds[3 + q] = bf2f(((const u16*)(hh ? h2h_b1 : h2o_b1))[jr]);  // ba[q]
    }
  }
  if (wv == 0) {
    if (rB >= 0) {                      // slot3: B-row (32+w) or OUTPUT
      const bool isout = (rB == 40);
      const u16* wb2 = isout ? w2o : w2h;
      const long rr  = isout ? 0 : rB;
      for (int i = 0; i < 20; ++i) {
        const u32 lo = wb2[rr * 40 + 2 * i];
        const u32 hi = wb2[rr * 40 + 2 * i + 1];
        dst[60 + i] = lo | (hi << 16);
      }
      ds[6] = isout ? bf2f(((const u16*)h2o_b2)[0])
                    : bf2f(((const u16*)h2h_b2)[rB]);
    }
  } else {
    for (int q = 0; q < 2; ++q) {       // slots 2,3: B-rows rB, rB+1
      const long r = rB + q;
      for (int i = 0; i < 20; ++i) {
        const u32 lo = w2h[r * 40 + 2 * i];
        const u32 hi = w2h[r * 40 + 2 * i + 1];
        dst[20 * (2 + q) + i] = lo | (hi << 16);
      }
      ds[6 + q] = bf2f(((const u16*)h2h_b2)[r]);
    }
  }
}

// ---- Main kernel, bf16 datasets: packed-ws weight stream ----
__global__ __launch_bounds__(128, 2)
void rnn_packed(const void* __restrict__ inp, const void* __restrict__ h2h_w1,
                const u32* __restrict__ ws, void* __restrict__ out) {
  __shared__ __align__(16) float sH[4][44];  // [el][k]  (R15 layout)
  __shared__ __align__(16) float sA[4][84];  // [el][j]

  if (!detect_bf16(h2h_w1)) return;   // bf16 datasets only

  const int tid  = threadIdx.x;
  const int lane = tid & 63;
  const int wv   = tid >> 6;
  const int el   = lane & 3;
  const int w    = wv * 16 + (lane >> 2);
  const int a0 = (wv == 0) ? 3 * w : 48 + 2 * (w - 16);
  const int nA = (wv == 0) ? 3 : 2;
  const int rB = (wv == 0) ? ((w < 8) ? 32 + w : ((w == 8) ? 40 : -1)) : 2 * (w - 16);

  // Per-thread packed weights: clean dwordx4-remat-able loads (ONE base,
  // immediate offsets). 1 u32 = 2 weights -> double resident coverage.
  const u32* wsp = ws + (long)tid * WSLICE;
  u32 wS[4][20];
#pragma unroll
  for (int q = 0; q < 4; ++q)
#pragma unroll
    for (int i = 0; i < 20; ++i) wS[q][i] = wsp[20 * q + i];
  const float* scal = (const float*)(wsp + 80);
  const float wu[3] = {scal[0], scal[1], scal[2]};
  const float ba[3] = {scal[3], scal[4], scal[5]};
  const float bb[2] = {scal[6], scal[7]};

  for (int i = tid; i < 4 * 44; i += 128) ((float*)sH)[i] = 0.f;
  __syncthreads();

  const int  b    = blockIdx.x * 4 + el;
  const long base = (long)b * T_SZ;
  float u_cur = bf2f(((const u16*)inp)[base]);

  for (int t = 0; t < T_SZ; ++t) {
    const float u_nxt = (t + 1 < T_SZ) ? bf2f(((const u16*)inp)[base + t + 1]) : 0.f;

    // ---------- Phase A: layer 1 (80 neurons) ----------
    f2 hv[20];
    {
      const f2* hp = (const f2*)sH[el];
#pragma unroll
      for (int i = 0; i < 20; ++i) hv[i] = hp[i];
    }
#pragma unroll
    for (int q = 0; q < 3; ++q) {
      if (q < nA) {   // wave-uniform
        f2 acc = {0.f, 0.f};
#pragma unroll
        for (int i = 0; i < 20; ++i)
          acc = hv[i] * bexp(wS[q][i]) + acc;   // v_pk_fma_f32
        const float a = fmaf(u_cur, wu[q], ba[q]) + acc.x + acc.y;
        sA[el][a0 + q] = fmaxf(a, 0.01f * a);   // LeakyReLU(0.01)
      }
    }
    __syncthreads();   // sA visible; all sH reads done

    // ---------- Phase B: layer 2 (rows 0..39 = hidden, 40 = output) ----------
    if (wv == 1) {     // uniform: 2 rows, a-acts
      f2 av[20];
      {
        const f2* ap = (const f2*)sA[el];
#pragma unroll
        for (int i = 0; i < 20; ++i) av[i] = ap[i];
      }
#pragma unroll
      for (int q = 0; q < 2; ++q) {
        f2 acc = {0.f, 0.f};
#pragma unroll
        for (int i = 0; i < 20; ++i)
          acc = av[i] * bexp(wS[2 + q][i]) + acc;
        sH[el][rB + q] = bb[q] + acc.x + acc.y;
      }
    } else if (rB >= 0) {   // wave 0: one row (32..39) or output row 40
      const f2* ap = (const f2*)(&sA[el][(rB == 40) ? 40 : 0]);  // 16B-aligned
      f2 av[20];
#pragma unroll
      for (int i = 0; i < 20; ++i) av[i] = ap[i];
      f2 acc = {0.f, 0.f};
#pragma unroll
      for (int i = 0; i < 20; ++i)
        acc = av[i] * bexp(wS[3][i]) + acc;
      const float a2 = bb[0] + acc.x + acc.y;
      if (rB < HID) sH[el][rB] = a2;
      else ((__hip_bfloat16*)out)[base + t] = __float2bfloat16(a2);
    }
    __syncthreads();   // sH update + sA reads done before next step

    u_cur = u_nxt;
  }
}

// ---- Fallback kernel: R15 verbatim (fp32 datasets, or ws too small) ----
template <bool BF>
__global__ __launch_bounds__(128, 2)
void rnn_generic(const void* __restrict__ inp,
                 const void* __restrict__ h2h_w1, const void* __restrict__ h2h_b1,
                 const void* __restrict__ h2h_w2, const void* __restrict__ h2h_b2,
                 const void* __restrict__ h2o_w1, const void* __restrict__ h2o_b1,
                 const void* __restrict__ h2o_w2, const void* __restrict__ h2o_b2,
                 void* __restrict__ out) {
  __shared__ __align__(16) float sH[4][44];
  __shared__ __align__(16) float sA[4][84];

  if (detect_bf16(h2h_w1) != BF) return;

  const int tid  = threadIdx.x;
  const int lane = tid & 63;
  const int wv   = tid >> 6;
  const int el   = lane & 3;
  const int w    = wv * 16 + (lane >> 2);
  const int a0 = (wv == 0) ? 3 * w : 48 + 2 * (w - 16);
  const int nA = (wv == 0) ? 3 : 2;
  const int rB = (wv == 0) ? ((w < 8) ? 32 + w : ((w == 8) ? 40 : -1)) : 2 * (w - 16);

  f2    wSf[4][20];
  float wu[3] = {0, 0, 0}, ba[3] = {0, 0, 0}, bb[2] = {0, 0};
#pragma unroll
  for (int q = 0; q < 3; ++q) {
    if (q < nA) {
      const int  j  = a0 + q;
      const bool hh = (j < HID);
      const void* wb1 = hh ? h2h_w1 : h2o_w1;
      const long  jr  = hh ? j : (j - HID);
      wu[q] = ldg<BF>(wb1, jr * 41);
      ba[q] = ldg<BF>(hh ? h2h_b1 : h2o_b1, jr);
#pragma unroll
      for (int i = 0; i < 20; ++i)
        wSf[q][i] = ldg2<BF>(wb1, jr * 41 + 1 + 2 * i);
    }
  }
  if (wv == 0) {
    if (rB >= 0) {
      const bool isout = (rB == 40);
      const void* wb2 = isout ? h2o_w2 : h2h_w2;
      const long  rr  = isout ? 0 : rB;
      bb[0] = isout ? ldg<BF>(h2o_b2, 0) : ldg<BF>(h2h_b2, rB);
#pragma unroll
      for (int i = 0; i < 20; ++i)
        wSf[3][i] = ldg2<BF>(wb2, rr * 40 + 2 * i);
    }
  } else {
#pragma unroll
    for (int q = 0; q < 2; ++q) {
      const long r = rB + q;
      bb[q] = ldg<BF>(h2h_b2, r);
#pragma unroll
      for (int i = 0; i < 20; ++i)
        wSf[2 + q][i] = ldg2<BF>(h2h_w2, r * 40 + 2 * i);
    }
  }

  for (int i = tid; i < 4 * 44; i += 128) ((float*)sH)[i] = 0.f;
  __syncthreads();

  const int  b    = blockIdx.x * 4 + el;
  const long base = (long)b * T_SZ;
  float u_cur = ldg<BF>(inp, base);

  for (int t = 0; t < T_SZ; ++t) {
    const float u_nxt = (t + 1 < T_SZ) ? ldg<BF>(inp, base + t + 1) : 0.f;

    f2 hv[20];
    {
      const f2* hp = (const f2*)sH[el];
#pragma unroll
      for (int i = 0; i < 20; ++i) hv[i] = hp[i];
    }
#pragma unroll
    for (int q = 0; q < 3; ++q) {
      if (q < nA) {
        f2 acc = {0.f, 0.f};
#pragma unroll
        for (int i = 0; i < 20; ++i)
          acc = hv[i] * wSf[q][i] + acc;
        const float a = fmaf(u_cur, wu[q], ba[q]) + acc.x + acc.y;
        sA[el][a0 + q] = fmaxf(a, 0.01f * a);
      }
    }
    __syncthreads();

    if (wv == 1) {
      f2 av[20];
      {
        const f2* ap = (const f2*)sA[el];
#pragma unroll
        for (int i = 0; i < 20; ++i) av[i] = ap[i];
      }
#pragma unroll
      for (int q = 0; q < 2; ++q) {
        f2 acc = {0.f, 0.f};
#pragma unroll
        for (int i = 0; i < 20; ++i)
          acc = av[i] * wSf[2 + q][i] + acc;
        sH[el][rB + q] = bb[q] + acc.x + acc.y;
      }
    } else if (rB >= 0) {
      const f2* ap = (const f2*)(&sA[el][(rB == 40) ? 40 : 0]);
      f2 av[20];
#pragma unroll
      for (int i = 0; i < 20; ++i) av[i] = ap[i];
      f2 acc = {0.f, 0.f};
#pragma unroll
      for (int i = 0; i < 20; ++i)
        acc = av[i] * wSf[3][i] + acc;
      const float a2 = bb[0] + acc.x + acc.y;
      if (rB < HID) {
        sH[el][rB] = a2;
      } else {
        if (BF) ((__hip_bfloat16*)out)[base + t] = __float2bfloat16(a2);
        else    ((float*)out)[base + t] = a2;
      }
    }
    __syncthreads();

    u_cur = u_nxt;
  }
}

extern "C" void kernel_launch(void* const* d_in, const int* in_sizes, int n_in,
                              void* d_out, int out_size, void* d_ws, size_t ws_size,
                              hipStream_t stream) {
  (void)in_sizes; (void)n_in; (void)out_size;
  const size_t need = (size_t)128 * WSLICE * sizeof(u32);   // 45 KB
  if (d_ws != nullptr && ws_size >= need) {
    // bf16 path: pack + packed kernel; fp32 path: generic fallback.
    pack_weights<<<dim3(1), dim3(128), 0, stream>>>(
        d_in[1], d_in[2], d_in[3], d_in[4],
        d_in[5], d_in[6], d_in[7], d_in[8], (u32*)d_ws);
    rnn_packed<<<dim3(B_SZ / 4), dim3(128), 0, stream>>>(
        d_in[0], d_in[1], (const u32*)d_ws, d_out);
    rnn_generic<false><<<dim3(B_SZ / 4), dim3(128), 0, stream>>>(
        d_in[0], d_in[1], d_in[2], d_in[3], d_in[4],
        d_in[5], d_in[6], d_in[7], d_in[8], d_out);
  } else {
    rnn_generic<false><<<dim3(B_SZ / 4), dim3(128), 0, stream>>>(
        d_in[0], d_in[1], d_in[2], d_in[3], d_in[4],
        d_in[5], d_in[6], d_in[7], d_in[8], d_out);
    rnn_generic<true><<<dim3(B_SZ / 4), dim3(128), 0, stream>>>(
        d_in[0], d_in[1], d_in[2], d_in[3], d_in[4],
        d_in[5], d_in[6], d_in[7], d_in[8], d_out);
  }
}